// Round 1
// baseline (623.954 us; speedup 1.0000x reference)
//
#include <hip/hip_runtime.h>

typedef __bf16 bf16x4 __attribute__((ext_vector_type(4)));
typedef __bf16 bf16x8 __attribute__((ext_vector_type(8)));
typedef float  f32x4  __attribute__((ext_vector_type(4)));

#define M_DIM 8192
#define N_DIM 4096
#define K_DIM 4096

// async global->LDS, 16B per lane; dest = wave-uniform base + lane*16 (linear)
#define GLDS16(gptr, lptr)                                                     \
  __builtin_amdgcn_global_load_lds(                                            \
      (const __attribute__((address_space(1))) void*)(gptr),                   \
      (__attribute__((address_space(3))) void*)(lptr), 16, 0, 0)

// ---------------- prep kernels ----------------

// one int32 word -> 8 bf16 (nibble e is bits [ (7-e)*4 .. ), i.e. (w<<4e)>>28)
__global__ __launch_bounds__(256) void dequant_w_kernel(
    const int* __restrict__ pw, const float* __restrict__ scale,
    unsigned short* __restrict__ wbf) {
  int idx = blockIdx.x * 256 + threadIdx.x;  // word index, 4096*512 total
  int o = idx >> 9;
  int p = idx & 511;
  int w = pw[idx];
  float s = scale[o * 32 + (p >> 4)];
  bf16x8 v;
#pragma unroll
  for (int e = 0; e < 8; ++e) {
    int val = (int)((unsigned)w << (4 * e)) >> 28;
    v[e] = (__bf16)((float)val * s);
  }
  *(bf16x8*)&wbf[(size_t)idx * 8] = v;
}

__global__ __launch_bounds__(256) void conv_x_kernel(
    const float* __restrict__ x, unsigned short* __restrict__ xbf) {
  size_t i = (size_t)(blockIdx.x * 256 + threadIdx.x) * 8;
  float4 a = *(const float4*)&x[i];
  float4 b = *(const float4*)&x[i + 4];
  bf16x8 v = {(__bf16)a.x, (__bf16)a.y, (__bf16)a.z, (__bf16)a.w,
              (__bf16)b.x, (__bf16)b.y, (__bf16)b.z, (__bf16)b.w};
  *(bf16x8*)&xbf[i] = v;
}

// ---------------- GEMM ----------------
// MODE 0: A from xbf via global_load_lds, B from wbf via global_load_lds
// MODE 1: A reg-staged from fp32 x (convert), B from wbf via global_load_lds
// MODE 2: A reg-staged from fp32 x, B reg-staged int4 dequant in-kernel
template <int MODE>
__global__ __launch_bounds__(256) void gemm_kernel(
    const float* __restrict__ x,          // [M][K] fp32
    const unsigned short* __restrict__ xbf,  // [M][K] bf16 (mode 0)
    const int* __restrict__ pw,           // [N][K/8] (mode 2)
    const float* __restrict__ scale,      // [N][K/128] (mode 2)
    const unsigned short* __restrict__ wbf,  // [N][K] bf16 (modes 0,1)
    const float* __restrict__ bias, float* __restrict__ out) {
  __shared__ unsigned short As[128 * 64];  // [m][k] 16 KB
  __shared__ unsigned short Bs[128 * 64];  // [n][k] 16 KB

  // XCD-aware bijective swizzle (2048 % 8 == 0)
  int bid = blockIdx.x;
  int cpx = gridDim.x >> 3;
  int swz = (bid & 7) * cpx + (bid >> 3);
  int bm = swz >> 5;            // N/128 = 32 tiles per row
  int bn = swz & 31;
  int m0 = bm * 128, n0 = bn * 128;

  int tid = threadIdx.x;
  int lane = tid & 63;
  int wave = tid >> 6;
  int wm = wave >> 1, wn = wave & 1;  // 2x2 waves of 64x64
  int lr = lane & 15;                 // fragment row/col
  int lk = lane >> 4;                 // k-group

  f32x4 acc[4][4];
#pragma unroll
  for (int i = 0; i < 4; ++i)
#pragma unroll
    for (int j = 0; j < 4; ++j) acc[i][j] = (f32x4)0.0f;

  int tr = tid >> 4, tc = tid & 15;  // A reg-stage mapping
  float4 ra[8];
  int4 rb;
  float sB = 0.f;

  if constexpr (MODE >= 1) {
#pragma unroll
    for (int i = 0; i < 8; ++i)
      ra[i] = *(const float4*)&x[(size_t)(m0 + i * 16 + tr) * K_DIM + tc * 4];
  }
  if constexpr (MODE == 2) {
    rb = *(const int4*)&pw[(size_t)(n0 + (tid >> 1)) * 512 + (tid & 1) * 4];
    sB = scale[(size_t)(n0 + (tid >> 1)) * 32 + 0];
  }

  const int NT = K_DIM / 64;
  for (int t = 0; t < NT; ++t) {
    int k0 = t * 64;
    // ---- stage A ----
    if constexpr (MODE == 0) {
#pragma unroll
      for (int j = 0; j < 4; ++j) {
        int c = wave * 4 + j;  // 8-row chunk
        const unsigned short* g = xbf +
            (size_t)(m0 + c * 8 + (lane >> 3)) * K_DIM + k0 + (lane & 7) * 8;
        GLDS16(g, (char*)As + c * 1024);
      }
    } else {
#pragma unroll
      for (int i = 0; i < 8; ++i) {
        float4 v = ra[i];
        bf16x4 b4 = {(__bf16)v.x, (__bf16)v.y, (__bf16)v.z, (__bf16)v.w};
        *(bf16x4*)&As[(i * 16 + tr) * 64 + tc * 4] = b4;
      }
    }
    // ---- stage B ----
    if constexpr (MODE <= 1) {
#pragma unroll
      for (int j = 0; j < 4; ++j) {
        int c = wave * 4 + j;
        const unsigned short* g = wbf +
            (size_t)(n0 + c * 8 + (lane >> 3)) * K_DIM + k0 + (lane & 7) * 8;
        GLDS16(g, (char*)Bs + c * 1024);
      }
    } else {
      int n = tid >> 1, h = tid & 1;
#pragma unroll
      for (int w = 0; w < 4; ++w) {
        int word = ((const int*)&rb)[w];
        bf16x8 o;
#pragma unroll
        for (int e = 0; e < 8; ++e) {
          int val = (int)((unsigned)word << (4 * e)) >> 28;
          o[e] = (__bf16)((float)val * sB);
        }
        *(bf16x8*)&Bs[n * 64 + h * 32 + w * 8] = o;
      }
    }
    // ---- prefetch next tile into regs (reg modes) ----
    if (t + 1 < NT) {
      int k1 = k0 + 64;
      if constexpr (MODE >= 1) {
#pragma unroll
        for (int i = 0; i < 8; ++i)
          ra[i] = *(const float4*)&x[(size_t)(m0 + i * 16 + tr) * K_DIM + k1 +
                                     tc * 4];
      }
      if constexpr (MODE == 2) {
        rb = *(const int4*)&pw[(size_t)(n0 + (tid >> 1)) * 512 + (k1 >> 3) +
                               (tid & 1) * 4];
        sB = scale[(size_t)(n0 + (tid >> 1)) * 32 + (k1 >> 7)];
      }
    }
    __syncthreads();  // LDS tile t ready (drains glds vmcnt / lgkm)
    // ---- compute ----
#pragma unroll
    for (int kk = 0; kk < 2; ++kk) {
      bf16x8 af[4], bfr[4];
#pragma unroll
      for (int mi = 0; mi < 4; ++mi)
        af[mi] = *(const bf16x8*)&As[(wm * 64 + mi * 16 + lr) * 64 + kk * 32 +
                                     lk * 8];
#pragma unroll
      for (int ni = 0; ni < 4; ++ni)
        bfr[ni] = *(const bf16x8*)&Bs[(wn * 64 + ni * 16 + lr) * 64 + kk * 32 +
                                      lk * 8];
#pragma unroll
      for (int mi = 0; mi < 4; ++mi)
#pragma unroll
        for (int ni = 0; ni < 4; ++ni)
          acc[mi][ni] = __builtin_amdgcn_mfma_f32_16x16x32_bf16(
              af[mi], bfr[ni], acc[mi][ni], 0, 0, 0);
    }
    __syncthreads();  // compute done, LDS reusable
  }

  // ---- epilogue: += bias, store fp32 ----
#pragma unroll
  for (int ni = 0; ni < 4; ++ni) {
    int col = n0 + wn * 64 + ni * 16 + lr;
    float bv = bias[col];
#pragma unroll
    for (int mi = 0; mi < 4; ++mi) {
      int rowb = m0 + wm * 64 + mi * 16 + lk * 4;
#pragma unroll
      for (int r = 0; r < 4; ++r)
        out[(size_t)(rowb + r) * N_DIM + col] = acc[mi][ni][r] + bv;
    }
  }
}

extern "C" void kernel_launch(void* const* d_in, const int* in_sizes, int n_in,
                              void* d_out, int out_size, void* d_ws,
                              size_t ws_size, hipStream_t stream) {
  const float* x = (const float*)d_in[0];
  const int* pw = (const int*)d_in[1];
  const float* scale = (const float*)d_in[2];
  const float* bias = (const float*)d_in[3];
  float* out = (float*)d_out;

  const size_t needB = (size_t)N_DIM * K_DIM * 2;  // 32 MB bf16 W
  const size_t needA = (size_t)M_DIM * K_DIM * 2;  // 64 MB bf16 x

  dim3 blk(256);
  dim3 grid((M_DIM / 128) * (N_DIM / 128));  // 2048

  if (ws_size >= needA + needB) {
    unsigned short* wbf = (unsigned short*)d_ws;
    unsigned short* xbf = (unsigned short*)((char*)d_ws + needB);
    dequant_w_kernel<<<(N_DIM * (K_DIM / 8)) / 256, blk, 0, stream>>>(pw, scale,
                                                                      wbf);
    conv_x_kernel<<<((size_t)M_DIM * K_DIM / 8) / 256, blk, 0, stream>>>(x,
                                                                         xbf);
    gemm_kernel<0><<<grid, blk, 0, stream>>>(x, xbf, pw, scale, wbf, bias,
                                             out);
  } else if (ws_size >= needB) {
    unsigned short* wbf = (unsigned short*)d_ws;
    dequant_w_kernel<<<(N_DIM * (K_DIM / 8)) / 256, blk, 0, stream>>>(pw, scale,
                                                                      wbf);
    gemm_kernel<1><<<grid, blk, 0, stream>>>(x, nullptr, pw, scale, wbf, bias,
                                             out);
  } else {
    gemm_kernel<2><<<grid, blk, 0, stream>>>(x, nullptr, pw, scale, nullptr,
                                             bias, out);
  }
}

// Round 3
// 456.822 us; speedup vs baseline: 1.3659x; 1.3659x over previous
//
#include <hip/hip_runtime.h>

typedef __bf16 bf16x4 __attribute__((ext_vector_type(4)));
typedef __bf16 bf16x8 __attribute__((ext_vector_type(8)));
typedef float  f32x4  __attribute__((ext_vector_type(4)));

#define M_DIM 8192
#define N_DIM 4096
#define K_DIM 4096

// async global->LDS, 16B/lane; LDS dest = wave-uniform base + lane*16 (linear)
#define GLDS16(gptr, lptr)                                                     \
  __builtin_amdgcn_global_load_lds(                                            \
      (const __attribute__((address_space(1))) void*)(gptr),                   \
      (__attribute__((address_space(3))) void*)(lptr), 16, 0, 0)

// ---------------- prep kernels ----------------

__global__ __launch_bounds__(256) void dequant_w_kernel(
    const int* __restrict__ pw, const float* __restrict__ scale,
    unsigned short* __restrict__ wbf) {
  int idx = blockIdx.x * 256 + threadIdx.x;  // word index
  int o = idx >> 9;
  int p = idx & 511;
  int w = pw[idx];
  float s = scale[o * 32 + (p >> 4)];
  bf16x8 v;
#pragma unroll
  for (int e = 0; e < 8; ++e) {
    int val = (int)((unsigned)w << (4 * e)) >> 28;
    v[e] = (__bf16)((float)val * s);
  }
  *(bf16x8*)&wbf[(size_t)idx * 8] = v;
}

__global__ __launch_bounds__(256) void conv_x_kernel(
    const float* __restrict__ x, unsigned short* __restrict__ xbf) {
  size_t i = (size_t)(blockIdx.x * 256 + threadIdx.x) * 8;
  float4 a = *(const float4*)&x[i];
  float4 b = *(const float4*)&x[i + 4];
  bf16x8 v = {(__bf16)a.x, (__bf16)a.y, (__bf16)a.z, (__bf16)a.w,
              (__bf16)b.x, (__bf16)b.y, (__bf16)b.z, (__bf16)b.w};
  *(bf16x8*)&xbf[i] = v;
}

// ---------------- 256x256 8-phase GEMM ----------------
// LDS map (bytes): A buf d at d*32768 (256 rows x 128B), B buf d at 65536+d*32768.
// Swizzle (involution, within 1KB = 8 rows): phys = logical ^ (((addr>>7)&7)<<4).
// glds writes linearly -> per-lane GLOBAL source pre-applies the inverse swizzle;
// ds_read applies it on the address. (rule 21: both-sides-or-neither)

template <int QM, int QN>
__device__ __forceinline__ void mfma_quad(f32x4 (&acc)[8][4],
                                          const bf16x8 (&a)[4][2],
                                          const bf16x8 (&b)[2][2]) {
  __builtin_amdgcn_s_setprio(1);
#pragma unroll
  for (int mi = 0; mi < 4; ++mi)
#pragma unroll
    for (int ni = 0; ni < 2; ++ni)
#pragma unroll
      for (int kk = 0; kk < 2; ++kk)
        acc[QM * 4 + mi][QN * 2 + ni] =
            __builtin_amdgcn_mfma_f32_16x16x32_bf16(
                a[mi][kk], b[ni][kk], acc[QM * 4 + mi][QN * 2 + ni], 0, 0, 0);
  __builtin_amdgcn_s_setprio(0);
}

// stage one A-quarter unit (rows {qm*64..+64} u {128+qm*64..+64}), 2 glds/thread
#define STAGE_A(qm_, tau_)                                                     \
  do {                                                                         \
    const int k0_ = ((tau_) & 63) * 64;                                        \
    char* const base_ = lds + ((tau_) & 1) * 32768;                            \
    const int c0_ = wave * 2, c1_ = wave * 2 + 1;                              \
    const int R0_ = (qm_) * 64 + (c0_ & 7) * 8 + (c0_ >> 3) * 128;             \
    const int R1_ = (qm_) * 64 + (c1_ & 7) * 8 + (c1_ >> 3) * 128;             \
    GLDS16(xbf + (size_t)(m0 + R0_ + rs8) * K_DIM + k0_ + cs8e,                \
           base_ + R0_ * 128);                                                 \
    GLDS16(xbf + (size_t)(m0 + R1_ + rs8) * K_DIM + k0_ + cs8e,                \
           base_ + R1_ * 128);                                                 \
  } while (0)

// stage one B-stripe unit (n-rows {qn*32+j*64 .. +32, j=0..3}), 2 glds/thread
#define STAGE_B(qn_, tau_)                                                     \
  do {                                                                         \
    const int k0_ = ((tau_) & 63) * 64;                                        \
    char* const base_ = lds + 65536 + ((tau_) & 1) * 32768;                    \
    const int c0_ = wave * 2, c1_ = wave * 2 + 1;                              \
    const int R0_ = (qn_) * 32 + (c0_ >> 2) * 64 + (c0_ & 3) * 8;              \
    const int R1_ = (qn_) * 32 + (c1_ >> 2) * 64 + (c1_ & 3) * 8;              \
    GLDS16(wbf + (size_t)(n0 + R0_ + rs8) * K_DIM + k0_ + cs8e,                \
           base_ + R0_ * 128);                                                 \
    GLDS16(wbf + (size_t)(n0 + R1_ + rs8) * K_DIM + k0_ + cs8e,                \
           base_ + R1_ * 128);                                                 \
  } while (0)

#define READ_A(d_, qm_)                                                        \
  do {                                                                         \
    const char* pA_ = lds + (d_) * 32768 + (qm_) * 8192 + aRowOff;             \
    a[0][0] = *(const bf16x8*)(pA_ + 0 + b0);                                  \
    a[0][1] = *(const bf16x8*)(pA_ + 0 + b1);                                  \
    a[1][0] = *(const bf16x8*)(pA_ + 2048 + b0);                               \
    a[1][1] = *(const bf16x8*)(pA_ + 2048 + b1);                               \
    a[2][0] = *(const bf16x8*)(pA_ + 4096 + b0);                               \
    a[2][1] = *(const bf16x8*)(pA_ + 4096 + b1);                               \
    a[3][0] = *(const bf16x8*)(pA_ + 6144 + b0);                               \
    a[3][1] = *(const bf16x8*)(pA_ + 6144 + b1);                               \
  } while (0)

#define READ_B(d_, qn_)                                                        \
  do {                                                                         \
    const char* pB_ = lds + 65536 + (d_) * 32768 + (qn_) * 4096 + bRowOff;     \
    b[0][0] = *(const bf16x8*)(pB_ + 0 + b0);                                  \
    b[0][1] = *(const bf16x8*)(pB_ + 0 + b1);                                  \
    b[1][0] = *(const bf16x8*)(pB_ + 2048 + b0);                               \
    b[1][1] = *(const bf16x8*)(pB_ + 2048 + b1);                               \
  } while (0)

#define PH_MID                                                                 \
  do {                                                                         \
    asm volatile("" ::: "memory");                                             \
    __builtin_amdgcn_s_barrier();                                              \
    asm volatile("s_waitcnt lgkmcnt(0)" ::: "memory");                         \
  } while (0)

#define PH_END                                                                 \
  do {                                                                         \
    asm volatile("" ::: "memory");                                             \
    __builtin_amdgcn_s_barrier();                                              \
  } while (0)

#define VMW6 asm volatile("s_waitcnt vmcnt(6)" ::: "memory")

__global__ __launch_bounds__(512, 2) void gemm8_kernel(
    const unsigned short* __restrict__ xbf,
    const unsigned short* __restrict__ wbf,
    const float* __restrict__ bias, float* __restrict__ out) {
  __shared__ char lds[131072];

  // XCD-aware bijective swizzle (512 blocks % 8 == 0)
  int bid = blockIdx.x;
  int cpx = gridDim.x >> 3;
  int swz = (bid & 7) * cpx + (bid >> 3);
  int bm = swz >> 4;  // 32 m-tiles
  int bn = swz & 15;  // 16 n-tiles
  int m0 = bm * 256, n0 = bn * 256;

  int tid = threadIdx.x;
  int lane = tid & 63;
  int wave = tid >> 6;                 // 0..7
  int wm = wave >> 2, wn = wave & 3;   // 2x4 waves; per-wave out 128x64
  int lr = lane & 15, lk = lane >> 4, l7 = lane & 7;

  const int rs8 = lane >> 3;                  // row-in-chunk for staging
  const int cs8e = ((lane & 7) ^ rs8) * 8;    // inverse-swizzled k-slot (elems)
  const int b0 = ((lk ^ l7) << 4);            // swizzled read byte off, kk=0
  const int b1 = b0 ^ 64;                     // kk=1
  const int aRowOff = (wm * 128 + lr) * 128;
  const int bRowOff = (wn * 64 + lr) * 128;

  f32x4 acc[8][4];
#pragma unroll
  for (int i = 0; i < 8; ++i)
#pragma unroll
    for (int jx = 0; jx < 4; ++jx) acc[i][jx] = (f32x4)0.0f;

  bf16x8 a[4][2], b[2][2];

  // ---- prologue: tile0 (4 units, buf0) then 3 units of tile1 (buf1) ----
  STAGE_A(0, 0);
  STAGE_B(1, 0);
  STAGE_A(1, 0);
  STAGE_B(0, 0);
  STAGE_A(0, 1);
  STAGE_B(1, 1);
  STAGE_A(1, 1);
  VMW6;  // confirms all 4 units of tile0; tile1 trio stays in flight
  asm volatile("" ::: "memory");
  __builtin_amdgcn_s_barrier();

  // ---- main loop: 2 K-tiles (t, t+1) per iteration, 8 phases ----
  for (int j = 0; j < K_DIM / 128; ++j) {
    int t = 2 * j;
    // ph1: q(0,0) of tile t (buf0)
    READ_A(0, 0);
    READ_B(0, 0);
    STAGE_B(0, t + 1);
    PH_MID;
    mfma_quad<0, 0>(acc, a, b);
    PH_END;
    // ph2: q(0,1)
    READ_B(0, 1);
    STAGE_A(0, t + 2);
    PH_MID;
    mfma_quad<0, 1>(acc, a, b);
    PH_END;
    // ph3: q(1,1)
    READ_A(0, 1);
    STAGE_B(1, t + 2);
    PH_MID;
    mfma_quad<1, 1>(acc, a, b);
    PH_END;
    // ph4: q(1,0)  (re-read B q0)
    READ_B(0, 0);
    STAGE_A(1, t + 2);
    VMW6;  // confirms tile t+1 complete
    PH_MID;
    mfma_quad<1, 0>(acc, a, b);
    PH_END;
    // ph5: q(0,0) of tile t+1 (buf1)
    READ_A(1, 0);
    READ_B(1, 0);
    STAGE_B(0, t + 2);
    PH_MID;
    mfma_quad<0, 0>(acc, a, b);
    PH_END;
    // ph6: q(0,1)
    READ_B(1, 1);
    STAGE_A(0, t + 3);
    PH_MID;
    mfma_quad<0, 1>(acc, a, b);
    PH_END;
    // ph7: q(1,1)
    READ_A(1, 1);
    STAGE_B(1, t + 3);
    PH_MID;
    mfma_quad<1, 1>(acc, a, b);
    PH_END;
    // ph8: q(1,0)
    READ_B(1, 0);
    STAGE_A(1, t + 3);
    VMW6;  // confirms tile t+2 complete
    PH_MID;
    mfma_quad<1, 0>(acc, a, b);
    PH_END;
  }

  // drain in-flight glds before workgroup retires (LDS gets reallocated)
  asm volatile("s_waitcnt vmcnt(0)" ::: "memory");

  // ---- epilogue: += bias, store fp32 ----
#pragma unroll
  for (int ng = 0; ng < 4; ++ng) {
    int col = n0 + wn * 64 + ng * 16 + lr;
    float bv = bias[col];
#pragma unroll
    for (int mg = 0; mg < 8; ++mg) {
      size_t rowb = (size_t)m0 + wm * 128 + mg * 16 + lk * 4;
#pragma unroll
      for (int r = 0; r < 4; ++r)
        out[(rowb + r) * N_DIM + col] = acc[mg][ng][r] + bv;
    }
  }
}

// ---------------- fallback (tiny ws): fused int4 dequant GEMM ----------------
__global__ __launch_bounds__(256) void gemm_fused_kernel(
    const float* __restrict__ x, const int* __restrict__ pw,
    const float* __restrict__ scale, const float* __restrict__ bias,
    float* __restrict__ out) {
  __shared__ unsigned short As[128 * 64];
  __shared__ unsigned short Bs[128 * 64];
  int bid = blockIdx.x;
  int cpx = gridDim.x >> 3;
  int swz = (bid & 7) * cpx + (bid >> 3);
  int bm = swz >> 5, bn = swz & 31;
  int m0 = bm * 128, n0 = bn * 128;
  int tid = threadIdx.x;
  int lane = tid & 63;
  int wave = tid >> 6;
  int wm = wave >> 1, wn = wave & 1;
  int lr = lane & 15, lk = lane >> 4;
  f32x4 acc[4][4];
#pragma unroll
  for (int i = 0; i < 4; ++i)
#pragma unroll
    for (int jx = 0; jx < 4; ++jx) acc[i][jx] = (f32x4)0.0f;
  int tr = tid >> 4, tc = tid & 15;
  float4 ra[8];
  int4 rb;
  float sB = 0.f;
#pragma unroll
  for (int i = 0; i < 8; ++i)
    ra[i] = *(const float4*)&x[(size_t)(m0 + i * 16 + tr) * K_DIM + tc * 4];
  rb = *(const int4*)&pw[(size_t)(n0 + (tid >> 1)) * 512 + (tid & 1) * 4];
  sB = scale[(size_t)(n0 + (tid >> 1)) * 32 + 0];
  const int NT = K_DIM / 64;
  for (int t = 0; t < NT; ++t) {
#pragma unroll
    for (int i = 0; i < 8; ++i) {
      float4 v = ra[i];
      bf16x4 b4 = {(__bf16)v.x, (__bf16)v.y, (__bf16)v.z, (__bf16)v.w};
      *(bf16x4*)&As[(i * 16 + tr) * 64 + tc * 4] = b4;
    }
    {
      int n = tid >> 1, h = tid & 1;
#pragma unroll
      for (int w = 0; w < 4; ++w) {
        int word = ((const int*)&rb)[w];
        bf16x8 o;
#pragma unroll
        for (int e = 0; e < 8; ++e) {
          int val = (int)((unsigned)word << (4 * e)) >> 28;
          o[e] = (__bf16)((float)val * sB);
        }
        *(bf16x8*)&Bs[n * 64 + h * 32 + w * 8] = o;
      }
    }
    if (t + 1 < NT) {
      int k1 = (t + 1) * 64;
#pragma unroll
      for (int i = 0; i < 8; ++i)
        ra[i] = *(const float4*)&x[(size_t)(m0 + i * 16 + tr) * K_DIM + k1 +
                                   tc * 4];
      rb = *(const int4*)&pw[(size_t)(n0 + (tid >> 1)) * 512 + (k1 >> 3) +
                             (tid & 1) * 4];
      sB = scale[(size_t)(n0 + (tid >> 1)) * 32 + (k1 >> 7)];
    }
    __syncthreads();
#pragma unroll
    for (int kk = 0; kk < 2; ++kk) {
      bf16x8 af[4], bfr[4];
#pragma unroll
      for (int mi = 0; mi < 4; ++mi)
        af[mi] = *(const bf16x8*)&As[(wm * 64 + mi * 16 + lr) * 64 + kk * 32 +
                                     lk * 8];
#pragma unroll
      for (int ni = 0; ni < 4; ++ni)
        bfr[ni] = *(const bf16x8*)&Bs[(wn * 64 + ni * 16 + lr) * 64 + kk * 32 +
                                      lk * 8];
#pragma unroll
      for (int mi = 0; mi < 4; ++mi)
#pragma unroll
        for (int ni = 0; ni < 4; ++ni)
          acc[mi][ni] = __builtin_amdgcn_mfma_f32_16x16x32_bf16(
              af[mi], bfr[ni], acc[mi][ni], 0, 0, 0);
    }
    __syncthreads();
  }
#pragma unroll
  for (int ni = 0; ni < 4; ++ni) {
    int col = n0 + wn * 64 + ni * 16 + lr;
    float bv = bias[col];
#pragma unroll
    for (int mi = 0; mi < 4; ++mi) {
      int rowb = m0 + wm * 64 + mi * 16 + lk * 4;
#pragma unroll
      for (int r = 0; r < 4; ++r)
        out[(size_t)(rowb + r) * N_DIM + col] = acc[mi][ni][r] + bv;
    }
  }
}

extern "C" void kernel_launch(void* const* d_in, const int* in_sizes, int n_in,
                              void* d_out, int out_size, void* d_ws,
                              size_t ws_size, hipStream_t stream) {
  const float* x = (const float*)d_in[0];
  const int* pw = (const int*)d_in[1];
  const float* scale = (const float*)d_in[2];
  const float* bias = (const float*)d_in[3];
  float* out = (float*)d_out;

  const size_t needB = (size_t)N_DIM * K_DIM * 2;  // 32 MB bf16 W
  const size_t needA = (size_t)M_DIM * K_DIM * 2;  // 64 MB bf16 x

  if (ws_size >= needA + needB) {
    unsigned short* wbf = (unsigned short*)d_ws;
    unsigned short* xbf = (unsigned short*)((char*)d_ws + needB);
    dequant_w_kernel<<<(N_DIM * (K_DIM / 8)) / 256, 256, 0, stream>>>(pw, scale,
                                                                      wbf);
    conv_x_kernel<<<((size_t)M_DIM * K_DIM / 8) / 256, 256, 0, stream>>>(x,
                                                                         xbf);
    gemm8_kernel<<<(M_DIM / 256) * (N_DIM / 256), 512, 0, stream>>>(xbf, wbf,
                                                                    bias, out);
  } else {
    gemm_fused_kernel<<<(M_DIM / 128) * (N_DIM / 128), 256, 0, stream>>>(
        x, pw, scale, bias, out);
  }
}

// Round 5
// 450.994 us; speedup vs baseline: 1.3835x; 1.0129x over previous
//
#include <hip/hip_runtime.h>

typedef __bf16 bf16x4 __attribute__((ext_vector_type(4)));
typedef __bf16 bf16x8 __attribute__((ext_vector_type(8)));
typedef float  f32x4  __attribute__((ext_vector_type(4)));

#define M_DIM 8192
#define N_DIM 4096
#define K_DIM 4096

// async global->LDS, 16B/lane; LDS dest = wave-uniform base + lane*16 (linear)
#define GLDS16(gptr, lptr)                                                     \
  __builtin_amdgcn_global_load_lds(                                            \
      (const __attribute__((address_space(1))) void*)(gptr),                   \
      (__attribute__((address_space(3))) void*)(lptr), 16, 0, 0)

// ---------------- prep kernels ----------------

__global__ __launch_bounds__(256) void dequant_w_kernel(
    const int* __restrict__ pw, const float* __restrict__ scale,
    unsigned short* __restrict__ wbf) {
  int idx = blockIdx.x * 256 + threadIdx.x;  // word index
  int o = idx >> 9;
  int p = idx & 511;
  int w = pw[idx];
  float s = scale[o * 32 + (p >> 4)];
  bf16x8 v;
#pragma unroll
  for (int e = 0; e < 8; ++e) {
    int val = (int)((unsigned)w << (4 * e)) >> 28;
    v[e] = (__bf16)((float)val * s);
  }
  *(bf16x8*)&wbf[(size_t)idx * 8] = v;
}

// fully coalesced: 16B/lane read, 8B/lane write
__global__ __launch_bounds__(256) void conv_x_kernel(
    const float* __restrict__ x, unsigned short* __restrict__ xbf) {
  size_t i = (size_t)(blockIdx.x * 256 + threadIdx.x) * 4;
  float4 a = *(const float4*)&x[i];
  bf16x4 v = {(__bf16)a.x, (__bf16)a.y, (__bf16)a.z, (__bf16)a.w};
  *(bf16x4*)&xbf[i] = v;
}

// ---------------- 256x256 8-phase GEMM ----------------
// LDS map (bytes): A buf d at d*32768 (256 rows x 128B), B buf d at 65536+d*32768.
// Swizzle (involution, within 1KB = 8 rows): phys = logical ^ (((addr>>7)&7)<<4).
// glds writes linearly -> per-lane GLOBAL source pre-applies the inverse swizzle;
// ds_read applies it on the address. (rule 21: both-sides-or-neither)

template <int QM, int QN>
__device__ __forceinline__ void mfma_quad(f32x4 (&acc)[8][4],
                                          const bf16x8 (&a)[4][2],
                                          const bf16x8 (&b)[2][2]) {
  __builtin_amdgcn_s_setprio(1);
#pragma unroll
  for (int mi = 0; mi < 4; ++mi)
#pragma unroll
    for (int ni = 0; ni < 2; ++ni)
#pragma unroll
      for (int kk = 0; kk < 2; ++kk)
        acc[QM * 4 + mi][QN * 2 + ni] =
            __builtin_amdgcn_mfma_f32_16x16x32_bf16(
                a[mi][kk], b[ni][kk], acc[QM * 4 + mi][QN * 2 + ni], 0, 0, 0);
  __builtin_amdgcn_s_setprio(0);
}

// stage one A-quarter unit (rows {qm*64..+64} u {128+qm*64..+64}), 2 glds/thread
#define STAGE_A(qm_, tau_)                                                     \
  do {                                                                         \
    const int k0_ = ((tau_) & 63) * 64;                                        \
    char* const base_ = lds + ((tau_) & 1) * 32768;                            \
    const int c0_ = wave * 2, c1_ = wave * 2 + 1;                              \
    const int R0_ = (qm_) * 64 + (c0_ & 7) * 8 + (c0_ >> 3) * 128;             \
    const int R1_ = (qm_) * 64 + (c1_ & 7) * 8 + (c1_ >> 3) * 128;             \
    GLDS16(xbf + (size_t)(m0 + R0_ + rs8) * K_DIM + k0_ + cs8e,                \
           base_ + R0_ * 128);                                                 \
    GLDS16(xbf + (size_t)(m0 + R1_ + rs8) * K_DIM + k0_ + cs8e,                \
           base_ + R1_ * 128);                                                 \
  } while (0)

// stage one B-stripe unit (n-rows {qn*32+j*64 .. +32, j=0..3}), 2 glds/thread
#define STAGE_B(qn_, tau_)                                                     \
  do {                                                                         \
    const int k0_ = ((tau_) & 63) * 64;                                        \
    char* const base_ = lds + 65536 + ((tau_) & 1) * 32768;                    \
    const int c0_ = wave * 2, c1_ = wave * 2 + 1;                              \
    const int R0_ = (qn_) * 32 + (c0_ >> 2) * 64 + (c0_ & 3) * 8;              \
    const int R1_ = (qn_) * 32 + (c1_ >> 2) * 64 + (c1_ & 3) * 8;              \
    GLDS16(wbf + (size_t)(n0 + R0_ + rs8) * K_DIM + k0_ + cs8e,                \
           base_ + R0_ * 128);                                                 \
    GLDS16(wbf + (size_t)(n0 + R1_ + rs8) * K_DIM + k0_ + cs8e,                \
           base_ + R1_ * 128);                                                 \
  } while (0)

#define READ_A(d_, qm_)                                                        \
  do {                                                                         \
    const char* pA_ = lds + (d_) * 32768 + (qm_) * 8192 + aRowOff;             \
    a[0][0] = *(const bf16x8*)(pA_ + 0 + b0);                                  \
    a[0][1] = *(const bf16x8*)(pA_ + 0 + b1);                                  \
    a[1][0] = *(const bf16x8*)(pA_ + 2048 + b0);                               \
    a[1][1] = *(const bf16x8*)(pA_ + 2048 + b1);                               \
    a[2][0] = *(const bf16x8*)(pA_ + 4096 + b0);                               \
    a[2][1] = *(const bf16x8*)(pA_ + 4096 + b1);                               \
    a[3][0] = *(const bf16x8*)(pA_ + 6144 + b0);                               \
    a[3][1] = *(const bf16x8*)(pA_ + 6144 + b1);                               \
  } while (0)

#define READ_B(d_, qn_, dst_)                                                  \
  do {                                                                         \
    const char* pB_ = lds + 65536 + (d_) * 32768 + (qn_) * 4096 + bRowOff;     \
    dst_[0][0] = *(const bf16x8*)(pB_ + 0 + b0);                               \
    dst_[0][1] = *(const bf16x8*)(pB_ + 0 + b1);                               \
    dst_[1][0] = *(const bf16x8*)(pB_ + 2048 + b0);                            \
    dst_[1][1] = *(const bf16x8*)(pB_ + 2048 + b1);                            \
  } while (0)

// NOTE: no lgkmcnt(0) here — compiler emits counted lgkm waits per MFMA
// operand, so the read-burst tail drains UNDER the MFMA cluster.
#define PH_MID                                                                 \
  do {                                                                         \
    asm volatile("" ::: "memory");                                             \
    __builtin_amdgcn_s_barrier();                                              \
  } while (0)

#define PH_END                                                                 \
  do {                                                                         \
    asm volatile("" ::: "memory");                                             \
    __builtin_amdgcn_s_barrier();                                              \
  } while (0)

#define VMW6 asm volatile("s_waitcnt vmcnt(6)" ::: "memory")

__global__ __launch_bounds__(512, 2) void gemm8_kernel(
    const unsigned short* __restrict__ xbf,
    const unsigned short* __restrict__ wbf,
    const float* __restrict__ bias, float* __restrict__ out) {
  __shared__ char lds[131072];

  // XCD-aware bijective swizzle (512 blocks % 8 == 0)
  int bid = blockIdx.x;
  int cpx = gridDim.x >> 3;
  int swz = (bid & 7) * cpx + (bid >> 3);
  int bm = swz >> 4;  // 32 m-tiles
  int bn = swz & 15;  // 16 n-tiles
  int m0 = bm * 256, n0 = bn * 256;

  int tid = threadIdx.x;
  int lane = tid & 63;
  int wave = tid >> 6;                 // 0..7
  int wm = wave >> 2, wn = wave & 3;   // 2x4 waves; per-wave out 128x64
  int lr = lane & 15, lk = lane >> 4, l7 = lane & 7;

  const int rs8 = lane >> 3;                  // row-in-chunk for staging
  const int cs8e = ((lane & 7) ^ rs8) * 8;    // inverse-swizzled k-slot (elems)
  const int b0 = ((lk ^ l7) << 4);            // swizzled read byte off, kk=0
  const int b1 = b0 ^ 64;                     // kk=1
  const int aRowOff = (wm * 128 + lr) * 128;
  const int bRowOff = (wn * 64 + lr) * 128;

  f32x4 acc[8][4];
#pragma unroll
  for (int i = 0; i < 8; ++i)
#pragma unroll
    for (int jx = 0; jx < 4; ++jx) acc[i][jx] = (f32x4)0.0f;

  bf16x8 a[4][2], bq0[2][2], bq1[2][2];

  // ---- prologue: tile0 (4 units, buf0) then 3 units of tile1 (buf1) ----
  STAGE_A(0, 0);
  STAGE_B(1, 0);
  STAGE_A(1, 0);
  STAGE_B(0, 0);
  STAGE_A(0, 1);
  STAGE_B(1, 1);
  STAGE_A(1, 1);
  VMW6;  // confirms all 4 units of tile0; tile1 trio stays in flight
  asm volatile("" ::: "memory");
  __builtin_amdgcn_s_barrier();

  // ---- main loop: 2 K-tiles (t, t+1) per iteration, 8 phases ----
  for (int j = 0; j < K_DIM / 128; ++j) {
    int t = 2 * j;
    // ph1: q(0,0) of tile t (buf0)
    READ_B(0, 0, bq0);
    READ_A(0, 0);
    STAGE_B(0, t + 1);
    PH_MID;
    mfma_quad<0, 0>(acc, a, bq0);
    PH_END;
    // ph2: q(0,1)
    READ_B(0, 1, bq1);
    STAGE_A(0, t + 2);
    PH_MID;
    mfma_quad<0, 1>(acc, a, bq1);
    PH_END;
    // ph3: q(1,1)
    READ_A(0, 1);
    STAGE_B(1, t + 2);
    PH_MID;
    mfma_quad<1, 1>(acc, a, bq1);
    PH_END;
    // ph4: q(1,0)  (bq0 kept in regs — no re-read)
    STAGE_A(1, t + 2);
    VMW6;  // confirms tile t+1 complete
    PH_MID;
    mfma_quad<1, 0>(acc, a, bq0);
    PH_END;
    // ph5: q(0,0) of tile t+1 (buf1)
    READ_B(1, 0, bq0);
    READ_A(1, 0);
    STAGE_B(0, t + 2);
    PH_MID;
    mfma_quad<0, 0>(acc, a, bq0);
    PH_END;
    // ph6: q(0,1)
    READ_B(1, 1, bq1);
    STAGE_A(0, t + 3);
    PH_MID;
    mfma_quad<0, 1>(acc, a, bq1);
    PH_END;
    // ph7: q(1,1)
    READ_A(1, 1);
    STAGE_B(1, t + 3);
    PH_MID;
    mfma_quad<1, 1>(acc, a, bq1);
    PH_END;
    // ph8: q(1,0)  (bq0 kept)
    STAGE_A(1, t + 3);
    VMW6;  // confirms tile t+2 complete
    PH_MID;
    mfma_quad<1, 0>(acc, a, bq0);
    PH_END;
  }

  // drain in-flight glds before workgroup retires (LDS gets reallocated)
  asm volatile("s_waitcnt vmcnt(0)" ::: "memory");

  // ---- epilogue: += bias, store fp32 ----
#pragma unroll
  for (int ng = 0; ng < 4; ++ng) {
    int col = n0 + wn * 64 + ng * 16 + lr;
    float bv = bias[col];
#pragma unroll
    for (int mg = 0; mg < 8; ++mg) {
      size_t rowb = (size_t)m0 + wm * 128 + mg * 16 + lk * 4;
#pragma unroll
      for (int r = 0; r < 4; ++r)
        out[(rowb + r) * N_DIM + col] = acc[mg][ng][r] + bv;
    }
  }
}

// ---------------- fallback (tiny ws): fused int4 dequant GEMM ----------------
__global__ __launch_bounds__(256) void gemm_fused_kernel(
    const float* __restrict__ x, const int* __restrict__ pw,
    const float* __restrict__ scale, const float* __restrict__ bias,
    float* __restrict__ out) {
  __shared__ unsigned short As[128 * 64];
  __shared__ unsigned short Bs[128 * 64];
  int bid = blockIdx.x;
  int cpx = gridDim.x >> 3;
  int swz = (bid & 7) * cpx + (bid >> 3);
  int bm = swz >> 5, bn = swz & 31;
  int m0 = bm * 128, n0 = bn * 128;
  int tid = threadIdx.x;
  int lane = tid & 63;
  int wave = tid >> 6;
  int wm = wave >> 1, wn = wave & 1;
  int lr = lane & 15, lk = lane >> 4;
  f32x4 acc[4][4];
#pragma unroll
  for (int i = 0; i < 4; ++i)
#pragma unroll
    for (int jx = 0; jx < 4; ++jx) acc[i][jx] = (f32x4)0.0f;
  int tr = tid >> 4, tc = tid & 15;
  float4 ra[8];
  int4 rb;
  float sB = 0.f;
#pragma unroll
  for (int i = 0; i < 8; ++i)
    ra[i] = *(const float4*)&x[(size_t)(m0 + i * 16 + tr) * K_DIM + tc * 4];
  rb = *(const int4*)&pw[(size_t)(n0 + (tid >> 1)) * 512 + (tid & 1) * 4];
  sB = scale[(size_t)(n0 + (tid >> 1)) * 32 + 0];
  const int NT = K_DIM / 64;
  for (int t = 0; t < NT; ++t) {
#pragma unroll
    for (int i = 0; i < 8; ++i) {
      float4 v = ra[i];
      bf16x4 b4 = {(__bf16)v.x, (__bf16)v.y, (__bf16)v.z, (__bf16)v.w};
      *(bf16x4*)&As[(i * 16 + tr) * 64 + tc * 4] = b4;
    }
    {
      int n = tid >> 1, h = tid & 1;
#pragma unroll
      for (int w = 0; w < 4; ++w) {
        int word = ((const int*)&rb)[w];
        bf16x8 o;
#pragma unroll
        for (int e = 0; e < 8; ++e) {
          int val = (int)((unsigned)word << (4 * e)) >> 28;
          o[e] = (__bf16)((float)val * sB);
        }
        *(bf16x8*)&Bs[n * 64 + h * 32 + w * 8] = o;
      }
    }
    if (t + 1 < NT) {
      int k1 = (t + 1) * 64;
#pragma unroll
      for (int i = 0; i < 8; ++i)
        ra[i] = *(const float4*)&x[(size_t)(m0 + i * 16 + tr) * K_DIM + k1 +
                                   tc * 4];
      rb = *(const int4*)&pw[(size_t)(n0 + (tid >> 1)) * 512 + (k1 >> 3) +
                             (tid & 1) * 4];
      sB = scale[(size_t)(n0 + (tid >> 1)) * 32 + (k1 >> 7)];
    }
    __syncthreads();
#pragma unroll
    for (int kk = 0; kk < 2; ++kk) {
      bf16x8 af[4], bfr[4];
#pragma unroll
      for (int mi = 0; mi < 4; ++mi)
        af[mi] = *(const bf16x8*)&As[(wm * 64 + mi * 16 + lr) * 64 + kk * 32 +
                                     lk * 8];
#pragma unroll
      for (int ni = 0; ni < 4; ++ni)
        bfr[ni] = *(const bf16x8*)&Bs[(wn * 64 + ni * 16 + lr) * 64 + kk * 32 +
                                      lk * 8];
#pragma unroll
      for (int mi = 0; mi < 4; ++mi)
#pragma unroll
        for (int ni = 0; ni < 4; ++ni)
          acc[mi][ni] = __builtin_amdgcn_mfma_f32_16x16x32_bf16(
              af[mi], bfr[ni], acc[mi][ni], 0, 0, 0);
    }
    __syncthreads();
  }
#pragma unroll
  for (int ni = 0; ni < 4; ++ni) {
    int col = n0 + wn * 64 + ni * 16 + lr;
    float bv = bias[col];
#pragma unroll
    for (int mi = 0; mi < 4; ++mi) {
      int rowb = m0 + wm * 64 + mi * 16 + lk * 4;
#pragma unroll
      for (int r = 0; r < 4; ++r)
        out[(size_t)(rowb + r) * N_DIM + col] = acc[mi][ni][r] + bv;
    }
  }
}

extern "C" void kernel_launch(void* const* d_in, const int* in_sizes, int n_in,
                              void* d_out, int out_size, void* d_ws,
                              size_t ws_size, hipStream_t stream) {
  const float* x = (const float*)d_in[0];
  const int* pw = (const int*)d_in[1];
  const float* scale = (const float*)d_in[2];
  const float* bias = (const float*)d_in[3];
  float* out = (float*)d_out;

  const size_t needB = (size_t)N_DIM * K_DIM * 2;  // 32 MB bf16 W
  const size_t needA = (size_t)M_DIM * K_DIM * 2;  // 64 MB bf16 x

  if (ws_size >= needA + needB) {
    unsigned short* wbf = (unsigned short*)d_ws;
    unsigned short* xbf = (unsigned short*)((char*)d_ws + needB);
    dequant_w_kernel<<<(N_DIM * (K_DIM / 8)) / 256, 256, 0, stream>>>(pw, scale,
                                                                      wbf);
    conv_x_kernel<<<((size_t)M_DIM * K_DIM / 4) / 256, 256, 0, stream>>>(x,
                                                                         xbf);
    gemm8_kernel<<<(M_DIM / 256) * (N_DIM / 256), 512, 0, stream>>>(xbf, wbf,
                                                                    bias, out);
  } else {
    gemm_fused_kernel<<<(M_DIM / 128) * (N_DIM / 128), 256, 0, stream>>>(
        x, pw, scale, bias, out);
  }
}